// Round 1
// baseline (10.248 us; speedup 1.0000x reference)
//
#include <hip/hip_runtime.h>
#include <math.h>

// Reference: tr = sum_i exp(W0[i,i]^2);  out = (tr - N)^2   (scalar fp32)
// Only the diagonal matters -> 8192 strided loads + reduction.

__global__ __launch_bounds__(1024) void diag_trace_loss_kernel(
    const float* __restrict__ W, float* __restrict__ out, int N) {
    const int tid = threadIdx.x;
    const size_t stride = (size_t)N + 1;  // diagonal stride in elements

    double acc = 0.0;
    for (int i = tid; i < N; i += 1024) {
        float x = W[(size_t)i * stride];
        acc += (double)expf(x * x);
    }

    // intra-wave reduction (wave = 64 lanes on gfx950)
    #pragma unroll
    for (int off = 32; off > 0; off >>= 1)
        acc += __shfl_down(acc, off, 64);

    __shared__ double wave_sums[16];  // 1024 threads / 64 = 16 waves
    const int lane = tid & 63;
    const int wave = tid >> 6;
    if (lane == 0) wave_sums[wave] = acc;
    __syncthreads();

    if (wave == 0) {
        double v = (lane < 16) ? wave_sums[lane] : 0.0;
        #pragma unroll
        for (int off = 8; off > 0; off >>= 1)
            v += __shfl_down(v, off, 64);
        if (lane == 0) {
            double d = v - (double)N;
            out[0] = (float)(d * d);
        }
    }
}

extern "C" void kernel_launch(void* const* d_in, const int* in_sizes, int n_in,
                              void* d_out, int out_size, void* d_ws, size_t ws_size,
                              hipStream_t stream) {
    const float* W = (const float*)d_in[0];
    float* out = (float*)d_out;

    // in_sizes[0] = N*N flat element count
    long long total = (long long)in_sizes[0];
    int N = (int)(sqrt((double)total) + 0.5);

    diag_trace_loss_kernel<<<1, 1024, 0, stream>>>(W, out, N);
}